// Round 8
// baseline (785.876 us; speedup 1.0000x reference)
//
#include <hip/hip_runtime.h>
#include <hip/hip_bf16.h>

// HGT forward, MI355X. Round 14: qkv grid 3.25x (RPB 208->64).
// R13 profile: qkv5 top (73us x2): MfmaUtil 8.4%, VALU 4.5%, HBM 29%,
// occ 17% -- GRID-STARVED: 481 blocks / 256 CUs = 1.9 blocks/CU x 4 waves
// = 7.5 waves/CU ceiling; store bursts + A-load latency unhidden. VGPR
// budget (128+40acc -> ~3 waves/SIMD) allows ~12 waves/CU: grid is the cap.
// Fix: RPB 208->64 -> qkv5 1563 blocks, qkv3 782. Preload (40 w-loads/wave)
// amortized over 4 iters instead of 13 -- extra weight reads are L2-resident
// (160KB total, ~5us aggregate at 34.5TB/s) in exchange for 2-3x TLP.
// agg_all (R13, 16-lane groups) / gemm_2t_reg / CSR / prep unchanged.

typedef __hip_bfloat16 bf16;
typedef __attribute__((ext_vector_type(8))) short short8;
typedef __attribute__((ext_vector_type(4))) short s4v;
typedef __attribute__((ext_vector_type(4))) float floatx4;

#define N_STMT 100000
#define N_FUNC 50000
#define N_TOT  150000
#define EDGES  200000
#define CCH 128
#define RPB 64     // rows/block, qkv kernels (4 iters of 16)
#define RPB2 96    // rows/block, 2t kernels (6 iters of 16)
#define GS2 1042   // ceil(100000/96)
#define GF2 521    // ceil(50000/96)

__device__ __forceinline__ float b2f(bf16 x){ return __bfloat162float(x); }
__device__ __forceinline__ float bs2f(short s){
  union { short s; bf16 h; } u; u.s = s; return __bfloat162float(u.h);
}
__device__ __forceinline__ short f2bs(float x){
  union { bf16 h; short s; } u; u.h = __float2bfloat16(x); return u.s;
}
__device__ __forceinline__ float blo(unsigned u){ return __uint_as_float(u << 16); }
__device__ __forceinline__ float bhi(unsigned u){ return __uint_as_float(u & 0xffff0000u); }
// tanh-form gelu via single exp: 0.5x(1+tanh(u)) = x - x/(e^{2u}+1)
__device__ __forceinline__ float gelu_f(float x){
  float z = 1.5957691216057308f * (x + 0.044715f * x * x * x);
  float t = __expf(z);
  return x - x / (t + 1.f);
}

// ---------------- emb fp32 -> bf16 table ------------------------------------
__global__ __launch_bounds__(256) void emb2bf(
    const float* __restrict__ emb, bf16* __restrict__ ebf)
{
  long i = ((long)blockIdx.x * 256 + threadIdx.x) * 8;
  float4 f0 = *(const float4*)(emb + i);
  float4 f1 = *(const float4*)(emb + i + 4);
  short8 o;
  o[0]=f2bs(f0.x); o[1]=f2bs(f0.y); o[2]=f2bs(f0.z); o[3]=f2bs(f0.w);
  o[4]=f2bs(f1.x); o[5]=f2bs(f1.y); o[6]=f2bs(f1.z); o[7]=f2bs(f1.w);
  *(short8*)(ebf + i) = o;
}

// ---------------- pooled embedding: one wave per node -----------------------
__global__ __launch_bounds__(256) void pool_embed(
    const int* __restrict__ tok_s, const int* __restrict__ tok_f,
    const bf16* __restrict__ ebf, bf16* __restrict__ E_out)
{
  int n = blockIdx.x * 4 + (threadIdx.x >> 6);
  int lane = threadIdx.x & 63, g = lane >> 4, c16 = lane & 15;
  const int* tok = (n < N_STMT) ? (tok_s + n * 16) : (tok_f + (n - N_STMT) * 16);
  float acc[8] = {0.f,0.f,0.f,0.f,0.f,0.f,0.f,0.f};
#pragma unroll
  for (int j = 0; j < 4; j++) {
    int v = tok[g * 4 + j];
    short8 row = *(const short8*)(ebf + (long)v * CCH + c16 * 8);
#pragma unroll
    for (int q = 0; q < 8; q++) acc[q] += bs2f(row[q]);
  }
#pragma unroll
  for (int q = 0; q < 8; q++) {
    acc[q] += __shfl_xor(acc[q], 16);
    acc[q] += __shfl_xor(acc[q], 32);
  }
  if (g == 0) {
    short8 o;
#pragma unroll
    for (int q = 0; q < 8; q++) o[q] = f2bs(fmaxf(acc[q] * (1.f/16.f), 0.f));
    *(short8*)(E_out + (long)n * CCH + c16 * 8) = o;
  }
}

// ---------------- transpose+cast 10 raw weight matrices ---------------------
__global__ __launch_bounds__(256) void transp_w(
    const float* __restrict__ lin_w, const float* __restrict__ qw,
    const float* __restrict__ aw, bf16* __restrict__ out)
{
  int mat = blockIdx.y;
  const float* src = (mat < 2) ? lin_w + mat * 16384
                   : (mat < 6) ? qw + (mat - 2) * 16384
                               : aw + (mat - 6) * 16384;
  bf16* dst = out + mat * 16384;
  int idx = blockIdx.x * 256 + threadIdx.x;       // n*128+k
  int n = idx >> 7, k = idx & 127;
  dst[idx] = __float2bfloat16(src[k * 128 + n]);
}

// -------- ALL fused relation weights in one dispatch ------------------------
__global__ __launch_bounds__(256) void make_wr_all(
    const float* __restrict__ kw, const float* __restrict__ kb,
    const float* __restrict__ vw, const float* __restrict__ vb,
    const float* __restrict__ a_rel, const float* __restrict__ m_rel,
    bf16* __restrict__ WRT, float* __restrict__ Bf)
{
  int y = blockIdx.y;
  bool isV = y >= 6;
  int z = isV ? y - 6 : y;
  int l = z / 3, r = z % 3, st = (r == 2) ? 1 : 0;
  const float* W   = (isV ? vw : kw) + (l * 2 + st) * 16384;
  const float* b   = (isV ? vb : kb) + (l * 2 + st) * 128;
  const float* rel = (isV ? m_rel : a_rel) + z * 2048;
  bf16* Wrt = WRT + y * 16384;
  float* br = Bf + y * 128;

  int idx = blockIdx.x * 256 + threadIdx.x;
  if (idx < 128 * 128) {
    int c = idx >> 7, o = idx & 127;
    int h = o >> 4, e = o & 15;
    float acc = 0.f;
#pragma unroll
    for (int d = 0; d < 16; d++)
      acc += W[c * 128 + h * 16 + d] * rel[h * 256 + d * 16 + e];
    Wrt[o * 128 + c] = __float2bfloat16(acc);
  }
  if (idx < 128) {
    int h = idx >> 4, e = idx & 15;
    float acc = 0.f;
#pragma unroll
    for (int d = 0; d < 16; d++)
      acc += b[h * 16 + d] * rel[h * 256 + d * 16 + e];
    br[idx] = acc;
  }
}

// -------- 2-type GEMM, register-resident weights (lin / out-proj) -----------
template <bool RELU, bool BLEND, bool OUT_BF16>
__global__ __launch_bounds__(256) void gemm_2t_reg(
    const bf16* __restrict__ Ab, const bf16* __restrict__ Wt0,
    const bf16* __restrict__ Wt1, const float* __restrict__ bias0,
    const float* __restrict__ bias1, const bf16* __restrict__ oldx,
    void* __restrict__ dstv, const float* __restrict__ skip2)
{
  const int wave = threadIdx.x >> 6, lane = threadIdx.x & 63;
  const int lane15 = lane & 15, quad = lane >> 4;
  const int jc0 = wave * 2;
  const int bid = blockIdx.x;
  const int type = (bid >= GS2);
  const long base = type ? (long)N_STMT * CCH : 0;
  const int Nrows = type ? N_FUNC : N_STMT;
  long row = (long)(type ? bid - GS2 : bid) * RPB2;
  long rowEnd = row + RPB2; if (rowEnd > Nrows) rowEnd = Nrows;
  const bf16* Wt = type ? Wt1 : Wt0;
  const float* bias = type ? bias1 : bias0;

  short8 w[2][4];
#pragma unroll
  for (int jj = 0; jj < 2; jj++)
#pragma unroll
    for (int kq = 0; kq < 4; kq++)
      w[jj][kq] = *(const short8*)(
          Wt + ((jc0 + jj) * 16 + lane15) * CCH + kq * 32 + quad * 8);
  float4 bb[2];
#pragma unroll
  for (int jj = 0; jj < 2; jj++)
    bb[jj] = *(const float4*)(bias + (jc0 + jj) * 16 + quad * 4);

  float g = 1.f, gi = 0.f;
  if (BLEND) {
    float sk = skip2[type];
    g = 1.f / (1.f + expf(-sk));
    gi = 1.f - g;
  }

  for (; row < rowEnd; row += 16) {
    long r = row + lane15;
    long rc = (r < Nrows) ? r : (Nrows - 1);
    short8 a[4];
#pragma unroll
    for (int kq = 0; kq < 4; kq++)
      a[kq] = *(const short8*)(Ab + base + rc * CCH + kq * 32 + quad * 8);

    floatx4 acc[2];
#pragma unroll
    for (int jj = 0; jj < 2; jj++) {
      acc[jj][0] = bb[jj].x; acc[jj][1] = bb[jj].y;
      acc[jj][2] = bb[jj].z; acc[jj][3] = bb[jj].w;
    }
#pragma unroll
    for (int kq = 0; kq < 4; kq++)
#pragma unroll
      for (int jj = 0; jj < 2; jj++)
        acc[jj] = __builtin_amdgcn_mfma_f32_16x16x32_bf16(
            w[jj][kq], a[kq], acc[jj], 0, 0, 0);

    if (r < Nrows) {
#pragma unroll
      for (int jj = 0; jj < 2; jj++) {
        int c0 = (jc0 + jj) * 16 + quad * 4;
        long idx = base + r * CCH + c0;
        float v[4];
#pragma unroll
        for (int q = 0; q < 4; q++) v[q] = acc[jj][q];
        if (RELU) {
#pragma unroll
          for (int q = 0; q < 4; q++) v[q] = fmaxf(v[q], 0.f);
        }
        if (BLEND) {
          s4v ov = *(const s4v*)(oldx + idx);
#pragma unroll
          for (int q = 0; q < 4; q++) v[q] = g * v[q] + gi * bs2f(ov[q]);
        }
        if (OUT_BF16) {
          s4v o;
#pragma unroll
          for (int q = 0; q < 4; q++) o[q] = f2bs(v[q]);
          *(s4v*)((bf16*)dstv + idx) = o;
        } else {
          float4 o = make_float4(v[0], v[1], v[2], v[3]);
          *(float4*)((float*)dstv + idx) = o;
        }
      }
    }
  }
}

// ------------ QKV GEMM, register-resident weights, jc-split waves -----------
template <int NM>
__global__ __launch_bounds__(256, 2) void gemm_qkv_reg(
    const bf16* __restrict__ Ab,
    const bf16* __restrict__ W0, const float* __restrict__ B0,
    const bf16* __restrict__ W1, const float* __restrict__ B1,
    const bf16* __restrict__ W2, const float* __restrict__ B2,
    const bf16* __restrict__ W3, const float* __restrict__ B3,
    const bf16* __restrict__ W4, const float* __restrict__ B4,
    bf16* __restrict__ Q, bf16* __restrict__ KV0, bf16* __restrict__ KV1,
    int N)
{
  const int wave = threadIdx.x >> 6, lane = threadIdx.x & 63;
  const int lane15 = lane & 15, quad = lane >> 4;
  const int jc0 = wave * 2;

  long row = (long)blockIdx.x * RPB;
  if (row >= N) return;
  long rowEnd = row + RPB; if (rowEnd > N) rowEnd = N;

  const bf16* Wm[5]  = {W0, W1, W2, W3, W4};
  const float* Bm[5] = {B0, B1, B2, B3, B4};

  short8 w[NM][2][4];
#pragma unroll
  for (int m = 0; m < NM; m++)
#pragma unroll
    for (int jj = 0; jj < 2; jj++)
#pragma unroll
      for (int kq = 0; kq < 4; kq++)
        w[m][jj][kq] = *(const short8*)(
            Wm[m] + ((jc0 + jj) * 16 + lane15) * CCH + kq * 32 + quad * 8);

  for (; row < rowEnd; row += 16) {
    long r = row + lane15;
    long rc = (r < N) ? r : (N - 1);
    short8 a[4];
#pragma unroll
    for (int kq = 0; kq < 4; kq++)
      a[kq] = *(const short8*)(Ab + rc * CCH + kq * 32 + quad * 8);

    floatx4 acc[NM][2];
#pragma unroll
    for (int m = 0; m < NM; m++)
#pragma unroll
      for (int jj = 0; jj < 2; jj++) {
        float4 bb = *(const float4*)(Bm[m] + (jc0 + jj) * 16 + quad * 4);
        acc[m][jj][0] = bb.x; acc[m][jj][1] = bb.y;
        acc[m][jj][2] = bb.z; acc[m][jj][3] = bb.w;
      }

#pragma unroll
    for (int kq = 0; kq < 4; kq++)
#pragma unroll
      for (int m = 0; m < NM; m++)
#pragma unroll
        for (int jj = 0; jj < 2; jj++)
          acc[m][jj] = __builtin_amdgcn_mfma_f32_16x16x32_bf16(
              w[m][jj][kq], a[kq], acc[m][jj], 0, 0, 0);

    if (r < N) {
#pragma unroll
      for (int jj = 0; jj < 2; jj++) {
        int c0 = (jc0 + jj) * 16 + quad * 4;
        s4v qo;
        qo[0] = f2bs(acc[0][jj][0]);
        qo[1] = f2bs(acc[0][jj][1]);
        qo[2] = f2bs(acc[0][jj][2]);
        qo[3] = f2bs(acc[0][jj][3]);
        *(s4v*)(Q + r * CCH + c0) = qo;

        short8 kv;
        kv[0] = f2bs(acc[1][jj][0]);
        kv[1] = f2bs(acc[1][jj][1]);
        kv[2] = f2bs(acc[2][jj][0]);
        kv[3] = f2bs(acc[2][jj][1]);
        kv[4] = f2bs(acc[1][jj][2]);
        kv[5] = f2bs(acc[1][jj][3]);
        kv[6] = f2bs(acc[2][jj][2]);
        kv[7] = f2bs(acc[2][jj][3]);
        *(short8*)(KV0 + r * 256 + 2 * c0) = kv;

        if constexpr (NM == 5) {
          kv[0] = f2bs(acc[3][jj][0]);
          kv[1] = f2bs(acc[3][jj][1]);
          kv[2] = f2bs(acc[4][jj][0]);
          kv[3] = f2bs(acc[4][jj][1]);
          kv[4] = f2bs(acc[3][jj][2]);
          kv[5] = f2bs(acc[3][jj][3]);
          kv[6] = f2bs(acc[4][jj][2]);
          kv[7] = f2bs(acc[4][jj][3]);
          *(short8*)(KV1 + r * 256 + 2 * c0) = kv;
        }
      }
    }
  }
}

// ---------------- CSR build (srcs stored directly) --------------------------
__global__ __launch_bounds__(256) void csr_count(
    const int* __restrict__ dst, int* __restrict__ deg, int* __restrict__ pos)
{
  int e = blockIdx.x * 256 + threadIdx.x;
  if (e < EDGES) pos[e] = atomicAdd(&deg[dst[e]], 1);
}
__global__ __launch_bounds__(256) void csr_alloc(
    const int* __restrict__ deg, int* __restrict__ rowstart,
    int* __restrict__ total, int Ndst)
{
  int n = blockIdx.x * 256 + threadIdx.x;
  if (n < Ndst) rowstart[n] = atomicAdd(total, deg[n]);
}
__global__ __launch_bounds__(256) void csr_fill(
    const int* __restrict__ dst, const int* __restrict__ src,
    const int* __restrict__ rowstart, const int* __restrict__ pos,
    int* __restrict__ srcs)
{
  int e = blockIdx.x * 256 + threadIdx.x;
  if (e < EDGES) srcs[rowstart[dst[e]] + pos[e]] = src[e];
}

// -------- per-relation message: 16-lane group, serial edges, no merges ------
__device__ __forceinline__ void relmsg_grp(
    int rs, int g, const int* __restrict__ srcs,
    const bf16* __restrict__ KV, float psc,
    const float* __restrict__ q, int lane, float* __restrict__ out)
{
  int p = lane & 15;
  int gbase = lane & 48;                 // first lane of this 16-lane group
  float den = 0.f;
  float a[8] = {0.f,0.f,0.f,0.f,0.f,0.f,0.f,0.f};
  for (int j0 = 0; j0 < g; j0 += 16) {
    int rem = g - j0; if (rem > 16) rem = 16;
    int sl = srcs[rs + j0 + (p < rem ? p : rem - 1)];
    for (int j = 0; j < rem; j++) {
      int s = __shfl(sl, gbase + j);
      const bf16* rowp = KV + (long)s * 256 + 16 * p;
      uint4 u0 = *(const uint4*)(rowp);
      uint4 u1 = *(const uint4*)(rowp + 8);
      // u0.x/u0.z/u1.x/u1.z = K pairs; u0.y/u0.w/u1.y/u1.w = V pairs
      float prod = q[0]*blo(u0.x) + q[1]*bhi(u0.x)
                 + q[2]*blo(u0.z) + q[3]*bhi(u0.z)
                 + q[4]*blo(u1.x) + q[5]*bhi(u1.x)
                 + q[6]*blo(u1.z) + q[7]*bhi(u1.z);
      prod += __shfl_xor(prod, 1);
      float ev = __expf(prod * psc);
      den += ev;
      a[0] += ev * blo(u0.y); a[1] += ev * bhi(u0.y);
      a[2] += ev * blo(u0.w); a[3] += ev * bhi(u0.w);
      a[4] += ev * blo(u1.y); a[5] += ev * bhi(u1.y);
      a[6] += ev * blo(u1.w); a[7] += ev * bhi(u1.w);
    }
  }
  float inv = 1.f / (den + 1e-16f);
#pragma unroll
  for (int i = 0; i < 8; i++) out[i] = a[i] * inv;
}

// -------- fused aggregation + GELU: 16 nodes per block (4 per wave) ---------
__global__ __launch_bounds__(256) void agg_all(
    const int* __restrict__ rs0, const int* __restrict__ dg0, const int* __restrict__ srcs0,
    const int* __restrict__ rs1, const int* __restrict__ dg1, const int* __restrict__ srcs1,
    const int* __restrict__ rs2, const int* __restrict__ dg2, const int* __restrict__ srcs2,
    const bf16* __restrict__ KV0, const bf16* __restrict__ KV1,
    const bf16* __restrict__ KV2, const float* __restrict__ pl,
    const bf16* __restrict__ Qb, bf16* __restrict__ AGGb)
{
  int n = blockIdx.x * 16 + (threadIdx.x >> 4);
  if (n >= N_TOT) return;
  int lane = threadIdx.x & 63;
  int p = lane & 15, h = p >> 1;
  uint4 qv = *(const uint4*)(Qb + (long)n * CCH + 8 * p);
  float q[8];
  q[0] = blo(qv.x); q[1] = bhi(qv.x); q[2] = blo(qv.y); q[3] = bhi(qv.y);
  q[4] = blo(qv.z); q[5] = bhi(qv.z); q[6] = blo(qv.w); q[7] = bhi(qv.w);
  float m[8];
  if (n < N_STMT) {
    float m0[8], m2[8];
    relmsg_grp(rs0[n], dg0[n], srcs0, KV0, pl[h] * 0.25f, q, lane, m0);
    relmsg_grp(rs2[n], dg2[n], srcs2, KV2, pl[16 + h] * 0.25f, q, lane, m2);
#pragma unroll
    for (int i = 0; i < 8; i++) m[i] = m0[i] + m2[i];
  } else {
    int nf = n - N_STMT;
    relmsg_grp(rs1[nf], dg1[nf], srcs1, KV1, pl[8 + h] * 0.25f, q, lane, m);
  }
  short8 o;
#pragma unroll
  for (int i = 0; i < 8; i++) o[i] = f2bs(gelu_f(m[i]));
  *(short8*)(AGGb + (long)n * CCH + 8 * p) = o;
}

__global__ __launch_bounds__(256) void zero_out_k(float* __restrict__ out)
{
  long i = ((long)blockIdx.x * 256 + threadIdx.x) * 4;
  *(float4*)(out + i) = make_float4(0.f, 0.f, 0.f, 0.f);
}

extern "C" void kernel_launch(void* const* d_in, const int* in_sizes, int n_in,
                              void* d_out, int out_size, void* d_ws, size_t ws_size,
                              hipStream_t stream)
{
  const int* tok_s = (const int*)d_in[0];
  const int* tok_f = (const int*)d_in[1];
  const int* esrc[3] = {(const int*)d_in[2], (const int*)d_in[4], (const int*)d_in[6]};
  const int* edst[3] = {(const int*)d_in[3], (const int*)d_in[5], (const int*)d_in[7]};
  const float* emb   = (const float*)d_in[8];
  const float* lin_w = (const float*)d_in[9];
  const float* lin_b = (const float*)d_in[10];
  const float* kw = (const float*)d_in[11];
  const float* kb = (const float*)d_in[12];
  const float* qw = (const float*)d_in[13];
  const float* qb = (const float*)d_in[14];
  const float* vw = (const float*)d_in[15];
  const float* vb = (const float*)d_in[16];
  const float* aw = (const float*)d_in[17];
  const float* ab = (const float*)d_in[18];
  const float* skip  = (const float*)d_in[19];
  const float* a_rel = (const float*)d_in[20];
  const float* m_rel = (const float*)d_in[21];
  const float* p_rel = (const float*)d_in[22];

  // ---- ws layout. Total 210,727,056 B. ----
  float* Bf   = (float*)d_ws;           // 12 x 128 fused biases
  bf16*  Xb   = (bf16*)(Bf + 1536);     // 19,200,000  residual stream
  bf16*  AGGb = Xb  + 19200000L;        // 19,200,000  (alias: pooled E)
  bf16*  KV0  = AGGb + 19200000L;       // 25,600,000  stmt r0 KV interleaved
  bf16*  KV1  = KV0 + 25600000L;        // 25,600,000  stmt r1 KV
  bf16*  KV2  = KV1 + 25600000L;        // 12,800,000  func r2 KV
  bf16*  WT   = KV2 + 12800000L;        //    163,840  10 transposed raw mats
  bf16*  WRT  = WT  + 163840L;          //    196,608  12 fused rel mats
  int*   ip   = (int*)(WRT + 196608L);
  int* deg[3]      = {ip, ip + 100000, ip + 150000};
  int* total       = ip + 250000;                      // 4 counters (3 used)
  int* rowstart[3] = {ip + 250004, ip + 350004, ip + 400004};
  int* srcs[3]     = {ip + 500004, ip + 700004, ip + 900004};
  int* pos         = ip + 1100004;                     // 200,000 (shared)
  bf16* EBF   = KV0;                    // 6,400,000 alias: bf16 emb table,
                                        // dead before KV0 is first written
  bf16*  Qb   = (bf16*)d_out;          // bf16 Q scratch in fp32 d_out,
  float* OUTF = (float*)d_out;         // consumed before epilogue overwrites

  const size_t NEED = (size_t)1536 * 4 + (size_t)102760448 * 2
                    + (size_t)1300004 * 4;
  if (ws_size < NEED) {            // soft-fail diagnostic: absmax == |ref|max
    zero_out_k<<<19200000 / 4 / 256, 256, 0, stream>>>(OUTF);
    return;
  }

  const int  Ntype[2] = {N_STMT, N_FUNC};
  const int  edt[3] = {0, 1, 0};
  const int  EB = (EDGES + 255) / 256;

  // ---- CSR build (per relation), reused by both layers ----
  hipMemsetAsync(ip, 0, (size_t)250004 * 4, stream);
  for (int r = 0; r < 3; r++) {
    int Nd = Ntype[edt[r]];
    csr_count<<<EB, 256, 0, stream>>>(edst[r], deg[r], pos);
    csr_alloc<<<(Nd + 255) / 256, 256, 0, stream>>>(deg[r], rowstart[r], total + r, Nd);
    csr_fill<<<EB, 256, 0, stream>>>(edst[r], esrc[r], rowstart[r], pos, srcs[r]);
  }

  // ---- one-time prep ----
  emb2bf<<<3125, 256, 0, stream>>>(emb, EBF);
  transp_w<<<dim3(64, 10), 256, 0, stream>>>(lin_w, qw, aw, WT);
  make_wr_all<<<dim3(64, 12), 256, 0, stream>>>(kw, kb, vw, vb, a_rel, m_rel, WRT, Bf);

  // ---- prologue: pooled embeddings -> fused per-type linear+relu -> Xb ----
  pool_embed<<<N_TOT / 4, 256, 0, stream>>>(tok_s, tok_f, EBF, AGGb);
  gemm_2t_reg<true, false, true><<<GS2 + GF2, 256, 0, stream>>>(
      AGGb, WT, WT + 16384, lin_b, lin_b + 128, nullptr, Xb, nullptr);

  const int GQS = (N_STMT + RPB - 1) / RPB;   // 1563
  const int GQF = (N_FUNC + RPB - 1) / RPB;   // 782

  for (int l = 0; l < 2; l++) {
    int z0 = l * 3 + 0, z1 = l * 3 + 1, z2 = l * 3 + 2;
    // stmt: Q + KV(r0) + KV(r1), X read once, weights in registers
    gemm_qkv_reg<5><<<GQS, 256, 0, stream>>>(
        Xb,
        WT + (2 + l * 2) * 16384, qb + (l * 2) * 128,
        WRT + z0 * 16384, Bf + z0 * 128,
        WRT + (6 + z0) * 16384, Bf + (6 + z0) * 128,
        WRT + z1 * 16384, Bf + z1 * 128,
        WRT + (6 + z1) * 16384, Bf + (6 + z1) * 128,
        Qb, KV0, KV1, N_STMT);
    // func: Q + KV(r2)
    gemm_qkv_reg<3><<<GQF, 256, 0, stream>>>(
        Xb + (long)N_STMT * CCH,
        WT + (2 + l * 2 + 1) * 16384, qb + (l * 2 + 1) * 128,
        WRT + z2 * 16384, Bf + z2 * 128,
        WRT + (6 + z2) * 16384, Bf + (6 + z2) * 128,
        nullptr, nullptr, nullptr, nullptr,
        Qb + (long)N_STMT * CCH, KV2, nullptr, N_FUNC);
    // fused aggregation (+GELU) over all nodes, 16 nodes/block
    agg_all<<<(N_TOT + 15) / 16, 256, 0, stream>>>(
        rowstart[0], deg[0], srcs[0], rowstart[1], deg[1], srcs[1],
        rowstart[2], deg[2], srcs[2], KV0, KV1, KV2,
        p_rel + l * 24, Qb, AGGb);
    // fused out-proj + gated skip blend. l=0 -> Xb; l=1 -> fp32 d_out.
    if (l == 0)
      gemm_2t_reg<false, true, true><<<GS2 + GF2, 256, 0, stream>>>(
          AGGb, WT + 6 * 16384, WT + 7 * 16384, ab, ab + 128,
          Xb, Xb, skip);
    else
      gemm_2t_reg<false, true, false><<<GS2 + GF2, 256, 0, stream>>>(
          AGGb, WT + 8 * 16384, WT + 9 * 16384, ab + 256, ab + 384,
          Xb, OUTF, skip + 2);
  }
}

// Round 9
// 730.170 us; speedup vs baseline: 1.0763x; 1.0763x over previous
//
#include <hip/hip_runtime.h>
#include <hip/hip_bf16.h>

// HGT forward, MI355X. Round 15: software-pipelined A-loads (vmcnt decoupling).
// R14 post-mortem: RPB 208->64 REGRESSED (73->97us) and occupancy stayed ~17%
// -> occupancy is REGISTER-capped (2 waves/SIMD), not grid-capped. Reverted
// RPB to 208. Real qkv bottleneck: loads+stores share vmcnt; the loop
// loads->MFMA->stores forces vmcnt(0) per iter = serial store-drain + full
// A-load latency, MFMA covers ~nothing (MfmaUtil 8.4%, 87% no-issue).
// Fix: double-buffer A in regs -- issue iter i+1's 4 A-loads BEFORE iter i's
// stores; the MFMA wait becomes vmcnt(9) (newer ops), store drain off the
// critical path, A-load gets a whole iteration of cover. +16 VGPR (~250,
// still 2 waves/SIMD). Same pipeline applied to gemm_2t_reg.
// agg_all (R13) / CSR / prep unchanged.

typedef __hip_bfloat16 bf16;
typedef __attribute__((ext_vector_type(8))) short short8;
typedef __attribute__((ext_vector_type(4))) short s4v;
typedef __attribute__((ext_vector_type(4))) float floatx4;

#define N_STMT 100000
#define N_FUNC 50000
#define N_TOT  150000
#define EDGES  200000
#define CCH 128
#define RPB 208    // rows/block, qkv kernels (13 iters of 16)
#define RPB2 96    // rows/block, 2t kernels (6 iters of 16)
#define GS2 1042   // ceil(100000/96)
#define GF2 521    // ceil(50000/96)

__device__ __forceinline__ float b2f(bf16 x){ return __bfloat162float(x); }
__device__ __forceinline__ float bs2f(short s){
  union { short s; bf16 h; } u; u.s = s; return __bfloat162float(u.h);
}
__device__ __forceinline__ short f2bs(float x){
  union { bf16 h; short s; } u; u.h = __float2bfloat16(x); return u.s;
}
__device__ __forceinline__ float blo(unsigned u){ return __uint_as_float(u << 16); }
__device__ __forceinline__ float bhi(unsigned u){ return __uint_as_float(u & 0xffff0000u); }
// tanh-form gelu via single exp: 0.5x(1+tanh(u)) = x - x/(e^{2u}+1)
__device__ __forceinline__ float gelu_f(float x){
  float z = 1.5957691216057308f * (x + 0.044715f * x * x * x);
  float t = __expf(z);
  return x - x / (t + 1.f);
}

// ---------------- emb fp32 -> bf16 table ------------------------------------
__global__ __launch_bounds__(256) void emb2bf(
    const float* __restrict__ emb, bf16* __restrict__ ebf)
{
  long i = ((long)blockIdx.x * 256 + threadIdx.x) * 8;
  float4 f0 = *(const float4*)(emb + i);
  float4 f1 = *(const float4*)(emb + i + 4);
  short8 o;
  o[0]=f2bs(f0.x); o[1]=f2bs(f0.y); o[2]=f2bs(f0.z); o[3]=f2bs(f0.w);
  o[4]=f2bs(f1.x); o[5]=f2bs(f1.y); o[6]=f2bs(f1.z); o[7]=f2bs(f1.w);
  *(short8*)(ebf + i) = o;
}

// ---------------- pooled embedding: one wave per node -----------------------
__global__ __launch_bounds__(256) void pool_embed(
    const int* __restrict__ tok_s, const int* __restrict__ tok_f,
    const bf16* __restrict__ ebf, bf16* __restrict__ E_out)
{
  int n = blockIdx.x * 4 + (threadIdx.x >> 6);
  int lane = threadIdx.x & 63, g = lane >> 4, c16 = lane & 15;
  const int* tok = (n < N_STMT) ? (tok_s + n * 16) : (tok_f + (n - N_STMT) * 16);
  float acc[8] = {0.f,0.f,0.f,0.f,0.f,0.f,0.f,0.f};
#pragma unroll
  for (int j = 0; j < 4; j++) {
    int v = tok[g * 4 + j];
    short8 row = *(const short8*)(ebf + (long)v * CCH + c16 * 8);
#pragma unroll
    for (int q = 0; q < 8; q++) acc[q] += bs2f(row[q]);
  }
#pragma unroll
  for (int q = 0; q < 8; q++) {
    acc[q] += __shfl_xor(acc[q], 16);
    acc[q] += __shfl_xor(acc[q], 32);
  }
  if (g == 0) {
    short8 o;
#pragma unroll
    for (int q = 0; q < 8; q++) o[q] = f2bs(fmaxf(acc[q] * (1.f/16.f), 0.f));
    *(short8*)(E_out + (long)n * CCH + c16 * 8) = o;
  }
}

// ---------------- transpose+cast 10 raw weight matrices ---------------------
__global__ __launch_bounds__(256) void transp_w(
    const float* __restrict__ lin_w, const float* __restrict__ qw,
    const float* __restrict__ aw, bf16* __restrict__ out)
{
  int mat = blockIdx.y;
  const float* src = (mat < 2) ? lin_w + mat * 16384
                   : (mat < 6) ? qw + (mat - 2) * 16384
                               : aw + (mat - 6) * 16384;
  bf16* dst = out + mat * 16384;
  int idx = blockIdx.x * 256 + threadIdx.x;       // n*128+k
  int n = idx >> 7, k = idx & 127;
  dst[idx] = __float2bfloat16(src[k * 128 + n]);
}

// -------- ALL fused relation weights in one dispatch ------------------------
__global__ __launch_bounds__(256) void make_wr_all(
    const float* __restrict__ kw, const float* __restrict__ kb,
    const float* __restrict__ vw, const float* __restrict__ vb,
    const float* __restrict__ a_rel, const float* __restrict__ m_rel,
    bf16* __restrict__ WRT, float* __restrict__ Bf)
{
  int y = blockIdx.y;
  bool isV = y >= 6;
  int z = isV ? y - 6 : y;
  int l = z / 3, r = z % 3, st = (r == 2) ? 1 : 0;
  const float* W   = (isV ? vw : kw) + (l * 2 + st) * 16384;
  const float* b   = (isV ? vb : kb) + (l * 2 + st) * 128;
  const float* rel = (isV ? m_rel : a_rel) + z * 2048;
  bf16* Wrt = WRT + y * 16384;
  float* br = Bf + y * 128;

  int idx = blockIdx.x * 256 + threadIdx.x;
  if (idx < 128 * 128) {
    int c = idx >> 7, o = idx & 127;
    int h = o >> 4, e = o & 15;
    float acc = 0.f;
#pragma unroll
    for (int d = 0; d < 16; d++)
      acc += W[c * 128 + h * 16 + d] * rel[h * 256 + d * 16 + e];
    Wrt[o * 128 + c] = __float2bfloat16(acc);
  }
  if (idx < 128) {
    int h = idx >> 4, e = idx & 15;
    float acc = 0.f;
#pragma unroll
    for (int d = 0; d < 16; d++)
      acc += b[h * 16 + d] * rel[h * 256 + d * 16 + e];
    br[idx] = acc;
  }
}

// -------- 2-type GEMM, register-resident weights, pipelined A ---------------
template <bool RELU, bool BLEND, bool OUT_BF16>
__global__ __launch_bounds__(256) void gemm_2t_reg(
    const bf16* __restrict__ Ab, const bf16* __restrict__ Wt0,
    const bf16* __restrict__ Wt1, const float* __restrict__ bias0,
    const float* __restrict__ bias1, const bf16* __restrict__ oldx,
    void* __restrict__ dstv, const float* __restrict__ skip2)
{
  const int wave = threadIdx.x >> 6, lane = threadIdx.x & 63;
  const int lane15 = lane & 15, quad = lane >> 4;
  const int jc0 = wave * 2;
  const int bid = blockIdx.x;
  const int type = (bid >= GS2);
  const long base = type ? (long)N_STMT * CCH : 0;
  const int Nrows = type ? N_FUNC : N_STMT;
  long row = (long)(type ? bid - GS2 : bid) * RPB2;
  long rowEnd = row + RPB2; if (rowEnd > Nrows) rowEnd = Nrows;
  const bf16* Wt = type ? Wt1 : Wt0;
  const float* bias = type ? bias1 : bias0;

  short8 w[2][4];
#pragma unroll
  for (int jj = 0; jj < 2; jj++)
#pragma unroll
    for (int kq = 0; kq < 4; kq++)
      w[jj][kq] = *(const short8*)(
          Wt + ((jc0 + jj) * 16 + lane15) * CCH + kq * 32 + quad * 8);
  float4 bb[2];
#pragma unroll
  for (int jj = 0; jj < 2; jj++)
    bb[jj] = *(const float4*)(bias + (jc0 + jj) * 16 + quad * 4);

  float g = 1.f, gi = 0.f;
  if (BLEND) {
    float sk = skip2[type];
    g = 1.f / (1.f + expf(-sk));
    gi = 1.f - g;
  }

  // prime first A tile
  short8 a[4];
  {
    long r = row + lane15; if (r >= Nrows) r = Nrows - 1;
#pragma unroll
    for (int kq = 0; kq < 4; kq++)
      a[kq] = *(const short8*)(Ab + base + r * CCH + kq * 32 + quad * 8);
  }

  for (; row < rowEnd; row += 16) {
    // prefetch next tile BEFORE this iter's stores (vmcnt decoupling)
    short8 an[4];
    {
      long nrow = (row + 16 < rowEnd) ? row + 16 : row;
      long r = nrow + lane15; if (r >= Nrows) r = Nrows - 1;
#pragma unroll
      for (int kq = 0; kq < 4; kq++)
        an[kq] = *(const short8*)(Ab + base + r * CCH + kq * 32 + quad * 8);
    }

    floatx4 acc[2];
#pragma unroll
    for (int jj = 0; jj < 2; jj++) {
      acc[jj][0] = bb[jj].x; acc[jj][1] = bb[jj].y;
      acc[jj][2] = bb[jj].z; acc[jj][3] = bb[jj].w;
    }
#pragma unroll
    for (int kq = 0; kq < 4; kq++)
#pragma unroll
      for (int jj = 0; jj < 2; jj++)
        acc[jj] = __builtin_amdgcn_mfma_f32_16x16x32_bf16(
            w[jj][kq], a[kq], acc[jj], 0, 0, 0);

    long r = row + lane15;
    if (r < Nrows) {
#pragma unroll
      for (int jj = 0; jj < 2; jj++) {
        int c0 = (jc0 + jj) * 16 + quad * 4;
        long idx = base + r * CCH + c0;
        float v[4];
#pragma unroll
        for (int q = 0; q < 4; q++) v[q] = acc[jj][q];
        if (RELU) {
#pragma unroll
          for (int q = 0; q < 4; q++) v[q] = fmaxf(v[q], 0.f);
        }
        if (BLEND) {
          s4v ov = *(const s4v*)(oldx + idx);
#pragma unroll
          for (int q = 0; q < 4; q++) v[q] = g * v[q] + gi * bs2f(ov[q]);
        }
        if (OUT_BF16) {
          s4v o;
#pragma unroll
          for (int q = 0; q < 4; q++) o[q] = f2bs(v[q]);
          *(s4v*)((bf16*)dstv + idx) = o;
        } else {
          float4 o = make_float4(v[0], v[1], v[2], v[3]);
          *(float4*)((float*)dstv + idx) = o;
        }
      }
    }
#pragma unroll
    for (int kq = 0; kq < 4; kq++) a[kq] = an[kq];
  }
}

// ------------ QKV GEMM, register-resident weights, pipelined A --------------
template <int NM>
__global__ __launch_bounds__(256, 2) void gemm_qkv_reg(
    const bf16* __restrict__ Ab,
    const bf16* __restrict__ W0, const float* __restrict__ B0,
    const bf16* __restrict__ W1, const float* __restrict__ B1,
    const bf16* __restrict__ W2, const float* __restrict__ B2,
    const bf16* __restrict__ W3, const float* __restrict__ B3,
    const bf16* __restrict__ W4, const float* __restrict__ B4,
    bf16* __restrict__ Q, bf16* __restrict__ KV0, bf16* __restrict__ KV1,
    int N)
{
  const int wave = threadIdx.x >> 6, lane = threadIdx.x & 63;
  const int lane15 = lane & 15, quad = lane >> 4;
  const int jc0 = wave * 2;

  long row = (long)blockIdx.x * RPB;
  if (row >= N) return;
  long rowEnd = row + RPB; if (rowEnd > N) rowEnd = N;

  const bf16* Wm[5]  = {W0, W1, W2, W3, W4};
  const float* Bm[5] = {B0, B1, B2, B3, B4};

  short8 w[NM][2][4];
#pragma unroll
  for (int m = 0; m < NM; m++)
#pragma unroll
    for (int jj = 0; jj < 2; jj++)
#pragma unroll
      for (int kq = 0; kq < 4; kq++)
        w[m][jj][kq] = *(const short8*)(
            Wm[m] + ((jc0 + jj) * 16 + lane15) * CCH + kq * 32 + quad * 8);

  // prime first A tile
  short8 a[4];
  {
    long r = row + lane15; if (r >= N) r = N - 1;
#pragma unroll
    for (int kq = 0; kq < 4; kq++)
      a[kq] = *(const short8*)(Ab + r * CCH + kq * 32 + quad * 8);
  }

  for (; row < rowEnd; row += 16) {
    // prefetch next tile BEFORE this iter's stores (vmcnt decoupling)
    short8 an[4];
    {
      long nrow = (row + 16 < rowEnd) ? row + 16 : row;
      long r = nrow + lane15; if (r >= N) r = N - 1;
#pragma unroll
      for (int kq = 0; kq < 4; kq++)
        an[kq] = *(const short8*)(Ab + r * CCH + kq * 32 + quad * 8);
    }

    floatx4 acc[NM][2];
#pragma unroll
    for (int m = 0; m < NM; m++)
#pragma unroll
      for (int jj = 0; jj < 2; jj++) {
        float4 bb = *(const float4*)(Bm[m] + (jc0 + jj) * 16 + quad * 4);
        acc[m][jj][0] = bb.x; acc[m][jj][1] = bb.y;
        acc[m][jj][2] = bb.z; acc[m][jj][3] = bb.w;
      }

#pragma unroll
    for (int kq = 0; kq < 4; kq++)
#pragma unroll
      for (int m = 0; m < NM; m++)
#pragma unroll
        for (int jj = 0; jj < 2; jj++)
          acc[m][jj] = __builtin_amdgcn_mfma_f32_16x16x32_bf16(
              w[m][jj][kq], a[kq], acc[m][jj], 0, 0, 0);

    long r = row + lane15;
    if (r < N) {
#pragma unroll
      for (int jj = 0; jj < 2; jj++) {
        int c0 = (jc0 + jj) * 16 + quad * 4;
        s4v qo;
        qo[0] = f2bs(acc[0][jj][0]);
        qo[1] = f2bs(acc[0][jj][1]);
        qo[2] = f2bs(acc[0][jj][2]);
        qo[3] = f2bs(acc[0][jj][3]);
        *(s4v*)(Q + r * CCH + c0) = qo;

        short8 kv;
        kv[0] = f2bs(acc[1][jj][0]);
        kv[1] = f2bs(acc[1][jj][1]);
        kv[2] = f2bs(acc[2][jj][0]);
        kv[3] = f2bs(acc[2][jj][1]);
        kv[4] = f2bs(acc[1][jj][2]);
        kv[5] = f2bs(acc[1][jj][3]);
        kv[6] = f2bs(acc[2][jj][2]);
        kv[7] = f2bs(acc[2][jj][3]);
        *(short8*)(KV0 + r * 256 + 2 * c0) = kv;

        if constexpr (NM == 5) {
          kv[0] = f2bs(acc[3][jj][0]);
          kv[1] = f2bs(acc[3][jj][1]);
          kv[2] = f2bs(acc[4][jj][0]);
          kv[3] = f2bs(acc[4][jj][1]);
          kv[4] = f2bs(acc[3][jj][2]);
          kv[5] = f2bs(acc[3][jj][3]);
          kv[6] = f2bs(acc[4][jj][2]);
          kv[7] = f2bs(acc[4][jj][3]);
          *(short8*)(KV1 + r * 256 + 2 * c0) = kv;
        }
      }
    }
#pragma unroll
    for (int kq = 0; kq < 4; kq++) a[kq] = an[kq];
  }
}

// ---------------- CSR build (srcs stored directly) --------------------------
__global__ __launch_bounds__(256) void csr_count(
    const int* __restrict__ dst, int* __restrict__ deg, int* __restrict__ pos)
{
  int e = blockIdx.x * 256 + threadIdx.x;
  if (e < EDGES) pos[e] = atomicAdd(&deg[dst[e]], 1);
}
__global__ __launch_bounds__(256) void csr_alloc(
    const int* __restrict__ deg, int* __restrict__ rowstart,
    int* __restrict__ total, int Ndst)
{
  int n = blockIdx.x * 256 + threadIdx.x;
  if (n < Ndst) rowstart[n] = atomicAdd(total, deg[n]);
}
__global__ __launch_bounds__(256) void csr_fill(
    const int* __restrict__ dst, const int* __restrict__ src,
    const int* __restrict__ rowstart, const int* __restrict__ pos,
    int* __restrict__ srcs)
{
  int e = blockIdx.x * 256 + threadIdx.x;
  if (e < EDGES) srcs[rowstart[dst[e]] + pos[e]] = src[e];
}

// -------- per-relation message: 16-lane group, serial edges, no merges ------
__device__ __forceinline__ void relmsg_grp(
    int rs, int g, const int* __restrict__ srcs,
    const bf16* __restrict__ KV, float psc,
    const float* __restrict__ q, int lane, float* __restrict__ out)
{
  int p = lane & 15;
  int gbase = lane & 48;                 // first lane of this 16-lane group
  float den = 0.f;
  float a[8] = {0.f,0.f,0.f,0.f,0.f,0.f,0.f,0.f};
  for (int j0 = 0; j0 < g; j0 += 16) {
    int rem = g - j0; if (rem > 16) rem = 16;
    int sl = srcs[rs + j0 + (p < rem ? p : rem - 1)];
    for (int j = 0; j < rem; j++) {
      int s = __shfl(sl, gbase + j);
      const bf16* rowp = KV + (long)s * 256 + 16 * p;
      uint4 u0 = *(const uint4*)(rowp);
      uint4 u1 = *(const uint4*)(rowp + 8);
      // u0.x/u0.z/u1.x/u1.z = K pairs; u0.y/u0.w/u1.y/u1.w = V pairs
      float prod = q[0]*blo(u0.x) + q[1]*bhi(u0.x)
                 + q[2]*blo(u0.z) + q[3]*bhi(u0.z)
                 + q[4]*blo(u1.x) + q[5]*bhi(u1.x)
                 + q[6]*blo(u1.z) + q[7]*bhi(u1.z);
      prod += __shfl_xor(prod, 1);
      float ev = __expf(prod * psc);
      den += ev;
      a[0] += ev * blo(u0.y); a[1] += ev * bhi(u0.y);
      a[2] += ev * blo(u0.w); a[3] += ev * bhi(u0.w);
      a[4] += ev * blo(u1.y); a[5] += ev * bhi(u1.y);
      a[6] += ev * blo(u1.w); a[7] += ev * bhi(u1.w);
    }
  }
  float inv = 1.f / (den + 1e-16f);
#pragma unroll
  for (int i = 0; i < 8; i++) out[i] = a[i] * inv;
}

// -------- fused aggregation + GELU: 16 nodes per block (4 per wave) ---------
__global__ __launch_bounds__(256) void agg_all(
    const int* __restrict__ rs0, const int* __restrict__ dg0, const int* __restrict__ srcs0,
    const int* __restrict__ rs1, const int* __restrict__ dg1, const int* __restrict__ srcs1,
    const int* __restrict__ rs2, const int* __restrict__ dg2, const int* __restrict__ srcs2,
    const bf16* __restrict__ KV0, const bf16* __restrict__ KV1,
    const bf16* __restrict__ KV2, const float* __restrict__ pl,
    const bf16* __restrict__ Qb, bf16* __restrict__ AGGb)
{
  int n = blockIdx.x * 16 + (threadIdx.x >> 4);
  if (n >= N_TOT) return;
  int lane = threadIdx.x & 63;
  int p = lane & 15, h = p >> 1;
  uint4 qv = *(const uint4*)(Qb + (long)n * CCH + 8 * p);
  float q[8];
  q[0] = blo(qv.x); q[1] = bhi(qv.x); q[2] = blo(qv.y); q[3] = bhi(qv.y);
  q[4] = blo(qv.z); q[5] = bhi(qv.z); q[6] = blo(qv.w); q[7] = bhi(qv.w);
  float m[8];
  if (n < N_STMT) {
    float m0[8], m2[8];
    relmsg_grp(rs0[n], dg0[n], srcs0, KV0, pl[h] * 0.25f, q, lane, m0);
    relmsg_grp(rs2[n], dg2[n], srcs2, KV2, pl[16 + h] * 0.25f, q, lane, m2);
#pragma unroll
    for (int i = 0; i < 8; i++) m[i] = m0[i] + m2[i];
  } else {
    int nf = n - N_STMT;
    relmsg_grp(rs1[nf], dg1[nf], srcs1, KV1, pl[8 + h] * 0.25f, q, lane, m);
  }
  short8 o;
#pragma unroll
  for (int i = 0; i < 8; i++) o[i] = f2bs(gelu_f(m[i]));
  *(short8*)(AGGb + (long)n * CCH + 8 * p) = o;
}

__global__ __launch_bounds__(256) void zero_out_k(float* __restrict__ out)
{
  long i = ((long)blockIdx.x * 256 + threadIdx.x) * 4;
  *(float4*)(out + i) = make_float4(0.f, 0.f, 0.f, 0.f);
}

extern "C" void kernel_launch(void* const* d_in, const int* in_sizes, int n_in,
                              void* d_out, int out_size, void* d_ws, size_t ws_size,
                              hipStream_t stream)
{
  const int* tok_s = (const int*)d_in[0];
  const int* tok_f = (const int*)d_in[1];
  const int* esrc[3] = {(const int*)d_in[2], (const int*)d_in[4], (const int*)d_in[6]};
  const int* edst[3] = {(const int*)d_in[3], (const int*)d_in[5], (const int*)d_in[7]};
  const float* emb   = (const float*)d_in[8];
  const float* lin_w = (const float*)d_in[9];
  const float* lin_b = (const float*)d_in[10];
  const float* kw = (const float*)d_in[11];
  const float* kb = (const float*)d_in[12];
  const float* qw = (const float*)d_in[13];
  const float* qb = (const float*)d_in[14];
  const float* vw = (const float*)d_in[15];
  const float* vb = (const float*)d_in[16];
  const float* aw = (const float*)d_in[17];
  const float* ab = (const float*)d_in[18];
  const float* skip  = (const float*)d_in[19];
  const float* a_rel = (const float*)d_in[20];
  const float* m_rel = (const float*)d_in[21];
  const float* p_rel = (const float*)d_in[22];

  // ---- ws layout. Total 210,727,056 B. ----
  float* Bf   = (float*)d_ws;           // 12 x 128 fused biases
  bf16*  Xb   = (bf16*)(Bf + 1536);     // 19,200,000  residual stream
  bf16*  AGGb = Xb  + 19200000L;        // 19,200,000  (alias: pooled E)
  bf16*  KV0  = AGGb + 19200000L;       // 25,600,000  stmt r0 KV interleaved
  bf16*  KV1  = KV0 + 25600000L;        // 25,600,000  stmt r1 KV
  bf16*  KV2  = KV1 + 25600000L;        // 12,800,000  func r2 KV
  bf16*  WT   = KV2 + 12800000L;        //    163,840  10 transposed raw mats
  bf16*  WRT  = WT  + 163840L;          //    196,608  12 fused rel mats
  int*   ip   = (int*)(WRT + 196608L);
  int* deg[3]      = {ip, ip + 100000, ip + 150000};
  int* total       = ip + 250000;                      // 4 counters (3 used)
  int* rowstart[3] = {ip + 250004, ip + 350004, ip + 400004};
  int* srcs[3]     = {ip + 500004, ip + 700004, ip + 900004};
  int* pos         = ip + 1100004;                     // 200,000 (shared)
  bf16* EBF   = KV0;                    // 6,400,000 alias: bf16 emb table,
                                        // dead before KV0 is first written
  bf16*  Qb   = (bf16*)d_out;          // bf16 Q scratch in fp32 d_out,
  float* OUTF = (float*)d_out;         // consumed before epilogue overwrites

  const size_t NEED = (size_t)1536 * 4 + (size_t)102760448 * 2
                    + (size_t)1300004 * 4;
  if (ws_size < NEED) {            // soft-fail diagnostic: absmax == |ref|max
    zero_out_k<<<19200000 / 4 / 256, 256, 0, stream>>>(OUTF);
    return;
  }

  const int  Ntype[2] = {N_STMT, N_FUNC};
  const int  edt[3] = {0, 1, 0};
  const int  EB = (EDGES + 255) / 256;

  // ---- CSR build (per relation), reused by both layers ----
  hipMemsetAsync(ip, 0, (size_t)250004 * 4, stream);
  for (int r = 0; r < 3; r++) {
    int Nd = Ntype[edt[r]];
    csr_count<<<EB, 256, 0, stream>>>(edst[r], deg[r], pos);
    csr_alloc<<<(Nd + 255) / 256, 256, 0, stream>>>(deg[r], rowstart[r], total + r, Nd);
    csr_fill<<<EB, 256, 0, stream>>>(edst[r], esrc[r], rowstart[r], pos, srcs[r]);
  }

  // ---- one-time prep ----
  emb2bf<<<3125, 256, 0, stream>>>(emb, EBF);
  transp_w<<<dim3(64, 10), 256, 0, stream>>>(lin_w, qw, aw, WT);
  make_wr_all<<<dim3(64, 12), 256, 0, stream>>>(kw, kb, vw, vb, a_rel, m_rel, WRT, Bf);

  // ---- prologue: pooled embeddings -> fused per-type linear+relu -> Xb ----
  pool_embed<<<N_TOT / 4, 256, 0, stream>>>(tok_s, tok_f, EBF, AGGb);
  gemm_2t_reg<true, false, true><<<GS2 + GF2, 256, 0, stream>>>(
      AGGb, WT, WT + 16384, lin_b, lin_b + 128, nullptr, Xb, nullptr);

  const int GQS = (N_STMT + RPB - 1) / RPB;   // 481
  const int GQF = (N_FUNC + RPB - 1) / RPB;   // 241

  for (int l = 0; l < 2; l++) {
    int z0 = l * 3 + 0, z1 = l * 3 + 1, z2 = l * 3 + 2;
    // stmt: Q + KV(r0) + KV(r1), X read once, weights in registers
    gemm_qkv_reg<5><<<GQS, 256, 0, stream>>>(
        Xb,
        WT + (2 + l * 2) * 16384, qb + (l * 2) * 128,
        WRT + z0 * 16384, Bf + z0 * 128,
        WRT + (6 + z0) * 16384, Bf + (6 + z0) * 128,
        WRT + z1 * 16384, Bf + z1 * 128,
        WRT + (6 + z1) * 16384, Bf + (6 + z1) * 128,
        Qb, KV0, KV1, N_STMT);
    // func: Q + KV(r2)
    gemm_qkv_reg<3><<<GQF, 256, 0, stream>>>(
        Xb + (long)N_STMT * CCH,
        WT + (2 + l * 2 + 1) * 16384, qb + (l * 2 + 1) * 128,
        WRT + z2 * 16384, Bf + z2 * 128,
        WRT + (6 + z2) * 16384, Bf + (6 + z2) * 128,
        nullptr, nullptr, nullptr, nullptr,
        Qb + (long)N_STMT * CCH, KV2, nullptr, N_FUNC);
    // fused aggregation (+GELU) over all nodes, 16 nodes/block
    agg_all<<<(N_TOT + 15) / 16, 256, 0, stream>>>(
        rowstart[0], deg[0], srcs[0], rowstart[1], deg[1], srcs[1],
        rowstart[2], deg[2], srcs[2], KV0, KV1, KV2,
        p_rel + l * 24, Qb, AGGb);
    // fused out-proj + gated skip blend. l=0 -> Xb; l=1 -> fp32 d_out.
    if (l == 0)
      gemm_2t_reg<false, true, true><<<GS2 + GF2, 256, 0, stream>>>(
          AGGb, WT + 6 * 16384, WT + 7 * 16384, ab, ab + 128,
          Xb, Xb, skip);
    else
      gemm_2t_reg<false, true, false><<<GS2 + GF2, 256, 0, stream>>>(
          AGGb, WT + 8 * 16384, WT + 9 * 16384, ab + 256, ab + 384,
          Xb, OUTF, skip + 2);
  }
}

// Round 10
// 719.535 us; speedup vs baseline: 1.0922x; 1.0148x over previous
//
#include <hip/hip_runtime.h>
#include <hip/hip_bf16.h>

// HGT forward, MI355X. Round 16: split penta QKV -> occupancy-driven BW.
// R15 post-mortem: 1-deep prefetch was a wash (73->72.4us). Surviving model:
// hbm_gbps plateaus ~2.4 TB/s at occ 17% (2 waves/SIMD, reg-capped by 160
// VGPR of penta weights) -- achieved BW scales with waves in flight; 6.3 TB/s
// needs ~32 waves/CU. Fix: split penta into A=(Q,K0,V0) NM=3 (~150 regs,
// launch_bounds(256,3), RPB=128 -> 782 blocks = 3/CU) and B=(K1,V1) NM=2
// (~108 regs, (256,4), RPB=96 -> 1042 blocks = 4/CU). Cost: X re-read by B
// (+25.6MB/layer). Prefetch/copy dropped (proven useless at this bound).
// Decision rule: occ up but BW flat -> pivot to fp8 KV traffic cut.
// agg_all (R13) / gemm_2t_reg (R15) / CSR / prep unchanged.

typedef __hip_bfloat16 bf16;
typedef __attribute__((ext_vector_type(8))) short short8;
typedef __attribute__((ext_vector_type(4))) short s4v;
typedef __attribute__((ext_vector_type(4))) float floatx4;

#define N_STMT 100000
#define N_FUNC 50000
#define N_TOT  150000
#define EDGES  200000
#define CCH 128
#define RPB2 96    // rows/block, 2t kernels (6 iters of 16)
#define GS2 1042   // ceil(100000/96)
#define GF2 521    // ceil(50000/96)

__device__ __forceinline__ float b2f(bf16 x){ return __bfloat162float(x); }
__device__ __forceinline__ float bs2f(short s){
  union { short s; bf16 h; } u; u.s = s; return __bfloat162float(u.h);
}
__device__ __forceinline__ short f2bs(float x){
  union { bf16 h; short s; } u; u.h = __float2bfloat16(x); return u.s;
}
__device__ __forceinline__ float blo(unsigned u){ return __uint_as_float(u << 16); }
__device__ __forceinline__ float bhi(unsigned u){ return __uint_as_float(u & 0xffff0000u); }
// tanh-form gelu via single exp: 0.5x(1+tanh(u)) = x - x/(e^{2u}+1)
__device__ __forceinline__ float gelu_f(float x){
  float z = 1.5957691216057308f * (x + 0.044715f * x * x * x);
  float t = __expf(z);
  return x - x / (t + 1.f);
}

// ---------------- emb fp32 -> bf16 table ------------------------------------
__global__ __launch_bounds__(256) void emb2bf(
    const float* __restrict__ emb, bf16* __restrict__ ebf)
{
  long i = ((long)blockIdx.x * 256 + threadIdx.x) * 8;
  float4 f0 = *(const float4*)(emb + i);
  float4 f1 = *(const float4*)(emb + i + 4);
  short8 o;
  o[0]=f2bs(f0.x); o[1]=f2bs(f0.y); o[2]=f2bs(f0.z); o[3]=f2bs(f0.w);
  o[4]=f2bs(f1.x); o[5]=f2bs(f1.y); o[6]=f2bs(f1.z); o[7]=f2bs(f1.w);
  *(short8*)(ebf + i) = o;
}

// ---------------- pooled embedding: one wave per node -----------------------
__global__ __launch_bounds__(256) void pool_embed(
    const int* __restrict__ tok_s, const int* __restrict__ tok_f,
    const bf16* __restrict__ ebf, bf16* __restrict__ E_out)
{
  int n = blockIdx.x * 4 + (threadIdx.x >> 6);
  int lane = threadIdx.x & 63, g = lane >> 4, c16 = lane & 15;
  const int* tok = (n < N_STMT) ? (tok_s + n * 16) : (tok_f + (n - N_STMT) * 16);
  float acc[8] = {0.f,0.f,0.f,0.f,0.f,0.f,0.f,0.f};
#pragma unroll
  for (int j = 0; j < 4; j++) {
    int v = tok[g * 4 + j];
    short8 row = *(const short8*)(ebf + (long)v * CCH + c16 * 8);
#pragma unroll
    for (int q = 0; q < 8; q++) acc[q] += bs2f(row[q]);
  }
#pragma unroll
  for (int q = 0; q < 8; q++) {
    acc[q] += __shfl_xor(acc[q], 16);
    acc[q] += __shfl_xor(acc[q], 32);
  }
  if (g == 0) {
    short8 o;
#pragma unroll
    for (int q = 0; q < 8; q++) o[q] = f2bs(fmaxf(acc[q] * (1.f/16.f), 0.f));
    *(short8*)(E_out + (long)n * CCH + c16 * 8) = o;
  }
}

// ---------------- transpose+cast 10 raw weight matrices ---------------------
__global__ __launch_bounds__(256) void transp_w(
    const float* __restrict__ lin_w, const float* __restrict__ qw,
    const float* __restrict__ aw, bf16* __restrict__ out)
{
  int mat = blockIdx.y;
  const float* src = (mat < 2) ? lin_w + mat * 16384
                   : (mat < 6) ? qw + (mat - 2) * 16384
                               : aw + (mat - 6) * 16384;
  bf16* dst = out + mat * 16384;
  int idx = blockIdx.x * 256 + threadIdx.x;       // n*128+k
  int n = idx >> 7, k = idx & 127;
  dst[idx] = __float2bfloat16(src[k * 128 + n]);
}

// -------- ALL fused relation weights in one dispatch ------------------------
__global__ __launch_bounds__(256) void make_wr_all(
    const float* __restrict__ kw, const float* __restrict__ kb,
    const float* __restrict__ vw, const float* __restrict__ vb,
    const float* __restrict__ a_rel, const float* __restrict__ m_rel,
    bf16* __restrict__ WRT, float* __restrict__ Bf)
{
  int y = blockIdx.y;
  bool isV = y >= 6;
  int z = isV ? y - 6 : y;
  int l = z / 3, r = z % 3, st = (r == 2) ? 1 : 0;
  const float* W   = (isV ? vw : kw) + (l * 2 + st) * 16384;
  const float* b   = (isV ? vb : kb) + (l * 2 + st) * 128;
  const float* rel = (isV ? m_rel : a_rel) + z * 2048;
  bf16* Wrt = WRT + y * 16384;
  float* br = Bf + y * 128;

  int idx = blockIdx.x * 256 + threadIdx.x;
  if (idx < 128 * 128) {
    int c = idx >> 7, o = idx & 127;
    int h = o >> 4, e = o & 15;
    float acc = 0.f;
#pragma unroll
    for (int d = 0; d < 16; d++)
      acc += W[c * 128 + h * 16 + d] * rel[h * 256 + d * 16 + e];
    Wrt[o * 128 + c] = __float2bfloat16(acc);
  }
  if (idx < 128) {
    int h = idx >> 4, e = idx & 15;
    float acc = 0.f;
#pragma unroll
    for (int d = 0; d < 16; d++)
      acc += b[h * 16 + d] * rel[h * 256 + d * 16 + e];
    br[idx] = acc;
  }
}

// -------- 2-type GEMM, register-resident weights, pipelined A ---------------
template <bool RELU, bool BLEND, bool OUT_BF16>
__global__ __launch_bounds__(256) void gemm_2t_reg(
    const bf16* __restrict__ Ab, const bf16* __restrict__ Wt0,
    const bf16* __restrict__ Wt1, const float* __restrict__ bias0,
    const float* __restrict__ bias1, const bf16* __restrict__ oldx,
    void* __restrict__ dstv, const float* __restrict__ skip2)
{
  const int wave = threadIdx.x >> 6, lane = threadIdx.x & 63;
  const int lane15 = lane & 15, quad = lane >> 4;
  const int jc0 = wave * 2;
  const int bid = blockIdx.x;
  const int type = (bid >= GS2);
  const long base = type ? (long)N_STMT * CCH : 0;
  const int Nrows = type ? N_FUNC : N_STMT;
  long row = (long)(type ? bid - GS2 : bid) * RPB2;
  long rowEnd = row + RPB2; if (rowEnd > Nrows) rowEnd = Nrows;
  const bf16* Wt = type ? Wt1 : Wt0;
  const float* bias = type ? bias1 : bias0;

  short8 w[2][4];
#pragma unroll
  for (int jj = 0; jj < 2; jj++)
#pragma unroll
    for (int kq = 0; kq < 4; kq++)
      w[jj][kq] = *(const short8*)(
          Wt + ((jc0 + jj) * 16 + lane15) * CCH + kq * 32 + quad * 8);
  float4 bb[2];
#pragma unroll
  for (int jj = 0; jj < 2; jj++)
    bb[jj] = *(const float4*)(bias + (jc0 + jj) * 16 + quad * 4);

  float g = 1.f, gi = 0.f;
  if (BLEND) {
    float sk = skip2[type];
    g = 1.f / (1.f + expf(-sk));
    gi = 1.f - g;
  }

  // prime first A tile
  short8 a[4];
  {
    long r = row + lane15; if (r >= Nrows) r = Nrows - 1;
#pragma unroll
    for (int kq = 0; kq < 4; kq++)
      a[kq] = *(const short8*)(Ab + base + r * CCH + kq * 32 + quad * 8);
  }

  for (; row < rowEnd; row += 16) {
    // prefetch next tile BEFORE this iter's stores (vmcnt decoupling)
    short8 an[4];
    {
      long nrow = (row + 16 < rowEnd) ? row + 16 : row;
      long r = nrow + lane15; if (r >= Nrows) r = Nrows - 1;
#pragma unroll
      for (int kq = 0; kq < 4; kq++)
        an[kq] = *(const short8*)(Ab + base + r * CCH + kq * 32 + quad * 8);
    }

    floatx4 acc[2];
#pragma unroll
    for (int jj = 0; jj < 2; jj++) {
      acc[jj][0] = bb[jj].x; acc[jj][1] = bb[jj].y;
      acc[jj][2] = bb[jj].z; acc[jj][3] = bb[jj].w;
    }
#pragma unroll
    for (int kq = 0; kq < 4; kq++)
#pragma unroll
      for (int jj = 0; jj < 2; jj++)
        acc[jj] = __builtin_amdgcn_mfma_f32_16x16x32_bf16(
            w[jj][kq], a[kq], acc[jj], 0, 0, 0);

    long r = row + lane15;
    if (r < Nrows) {
#pragma unroll
      for (int jj = 0; jj < 2; jj++) {
        int c0 = (jc0 + jj) * 16 + quad * 4;
        long idx = base + r * CCH + c0;
        float v[4];
#pragma unroll
        for (int q = 0; q < 4; q++) v[q] = acc[jj][q];
        if (RELU) {
#pragma unroll
          for (int q = 0; q < 4; q++) v[q] = fmaxf(v[q], 0.f);
        }
        if (BLEND) {
          s4v ov = *(const s4v*)(oldx + idx);
#pragma unroll
          for (int q = 0; q < 4; q++) v[q] = g * v[q] + gi * bs2f(ov[q]);
        }
        if (OUT_BF16) {
          s4v o;
#pragma unroll
          for (int q = 0; q < 4; q++) o[q] = f2bs(v[q]);
          *(s4v*)((bf16*)dstv + idx) = o;
        } else {
          float4 o = make_float4(v[0], v[1], v[2], v[3]);
          *(float4*)((float*)dstv + idx) = o;
        }
      }
    }
#pragma unroll
    for (int kq = 0; kq < 4; kq++) a[kq] = an[kq];
  }
}

// ------------ QKV GEMM, register-resident weights, jc-split waves -----------
// NM=3,HASQ=true : mats {Q,K,V} -> Q + interleaved KV. ~150 regs, 3 w/SIMD.
// NM=2,HASQ=false: mats {K,V}   -> interleaved KV only. ~108 regs, 4 w/SIMD.
template <int NM, bool HASQ>
__global__ __launch_bounds__(256, (NM == 2 ? 4 : 3)) void gemm_qkv_reg(
    const bf16* __restrict__ Ab,
    const bf16* __restrict__ W0, const float* __restrict__ B0,
    const bf16* __restrict__ W1, const float* __restrict__ B1,
    const bf16* __restrict__ W2, const float* __restrict__ B2,
    bf16* __restrict__ Q, bf16* __restrict__ KV, int N, int rpb)
{
  const int wave = threadIdx.x >> 6, lane = threadIdx.x & 63;
  const int lane15 = lane & 15, quad = lane >> 4;
  const int jc0 = wave * 2;
  constexpr int KIDX = HASQ ? 1 : 0;
  constexpr int VIDX = KIDX + 1;

  long row = (long)blockIdx.x * rpb;
  if (row >= N) return;
  long rowEnd = row + rpb; if (rowEnd > N) rowEnd = N;

  const bf16* Wm[3]  = {W0, W1, W2};
  const float* Bm[3] = {B0, B1, B2};

  short8 w[NM][2][4];
#pragma unroll
  for (int m = 0; m < NM; m++)
#pragma unroll
    for (int jj = 0; jj < 2; jj++)
#pragma unroll
      for (int kq = 0; kq < 4; kq++)
        w[m][jj][kq] = *(const short8*)(
            Wm[m] + ((jc0 + jj) * 16 + lane15) * CCH + kq * 32 + quad * 8);

  for (; row < rowEnd; row += 16) {
    long r = row + lane15;
    long rc = (r < N) ? r : (N - 1);
    short8 a[4];
#pragma unroll
    for (int kq = 0; kq < 4; kq++)
      a[kq] = *(const short8*)(Ab + rc * CCH + kq * 32 + quad * 8);

    floatx4 acc[NM][2];
#pragma unroll
    for (int m = 0; m < NM; m++)
#pragma unroll
      for (int jj = 0; jj < 2; jj++) {
        float4 bb = *(const float4*)(Bm[m] + (jc0 + jj) * 16 + quad * 4);
        acc[m][jj][0] = bb.x; acc[m][jj][1] = bb.y;
        acc[m][jj][2] = bb.z; acc[m][jj][3] = bb.w;
      }

#pragma unroll
    for (int kq = 0; kq < 4; kq++)
#pragma unroll
      for (int m = 0; m < NM; m++)
#pragma unroll
        for (int jj = 0; jj < 2; jj++)
          acc[m][jj] = __builtin_amdgcn_mfma_f32_16x16x32_bf16(
              w[m][jj][kq], a[kq], acc[m][jj], 0, 0, 0);

    if (r < N) {
#pragma unroll
      for (int jj = 0; jj < 2; jj++) {
        int c0 = (jc0 + jj) * 16 + quad * 4;
        if constexpr (HASQ) {
          s4v qo;
          qo[0] = f2bs(acc[0][jj][0]);
          qo[1] = f2bs(acc[0][jj][1]);
          qo[2] = f2bs(acc[0][jj][2]);
          qo[3] = f2bs(acc[0][jj][3]);
          *(s4v*)(Q + r * CCH + c0) = qo;
        }
        short8 kv;
        kv[0] = f2bs(acc[KIDX][jj][0]);
        kv[1] = f2bs(acc[KIDX][jj][1]);
        kv[2] = f2bs(acc[VIDX][jj][0]);
        kv[3] = f2bs(acc[VIDX][jj][1]);
        kv[4] = f2bs(acc[KIDX][jj][2]);
        kv[5] = f2bs(acc[KIDX][jj][3]);
        kv[6] = f2bs(acc[VIDX][jj][2]);
        kv[7] = f2bs(acc[VIDX][jj][3]);
        *(short8*)(KV + r * 256 + 2 * c0) = kv;
      }
    }
  }
}

// ---------------- CSR build (srcs stored directly) --------------------------
__global__ __launch_bounds__(256) void csr_count(
    const int* __restrict__ dst, int* __restrict__ deg, int* __restrict__ pos)
{
  int e = blockIdx.x * 256 + threadIdx.x;
  if (e < EDGES) pos[e] = atomicAdd(&deg[dst[e]], 1);
}
__global__ __launch_bounds__(256) void csr_alloc(
    const int* __restrict__ deg, int* __restrict__ rowstart,
    int* __restrict__ total, int Ndst)
{
  int n = blockIdx.x * 256 + threadIdx.x;
  if (n < Ndst) rowstart[n] = atomicAdd(total, deg[n]);
}
__global__ __launch_bounds__(256) void csr_fill(
    const int* __restrict__ dst, const int* __restrict__ src,
    const int* __restrict__ rowstart, const int* __restrict__ pos,
    int* __restrict__ srcs)
{
  int e = blockIdx.x * 256 + threadIdx.x;
  if (e < EDGES) srcs[rowstart[dst[e]] + pos[e]] = src[e];
}

// -------- per-relation message: 16-lane group, serial edges, no merges ------
__device__ __forceinline__ void relmsg_grp(
    int rs, int g, const int* __restrict__ srcs,
    const bf16* __restrict__ KV, float psc,
    const float* __restrict__ q, int lane, float* __restrict__ out)
{
  int p = lane & 15;
  int gbase = lane & 48;                 // first lane of this 16-lane group
  float den = 0.f;
  float a[8] = {0.f,0.f,0.f,0.f,0.f,0.f,0.f,0.f};
  for (int j0 = 0; j0 < g; j0 += 16) {
    int rem = g - j0; if (rem > 16) rem = 16;
    int sl = srcs[rs + j0 + (p < rem ? p : rem - 1)];
    for (int j = 0; j < rem; j++) {
      int s = __shfl(sl, gbase + j);
      const bf16* rowp = KV + (long)s * 256 + 16 * p;
      uint4 u0 = *(const uint4*)(rowp);
      uint4 u1 = *(const uint4*)(rowp + 8);
      // u0.x/u0.z/u1.x/u1.z = K pairs; u0.y/u0.w/u1.y/u1.w = V pairs
      float prod = q[0]*blo(u0.x) + q[1]*bhi(u0.x)
                 + q[2]*blo(u0.z) + q[3]*bhi(u0.z)
                 + q[4]*blo(u1.x) + q[5]*bhi(u1.x)
                 + q[6]*blo(u1.z) + q[7]*bhi(u1.z);
      prod += __shfl_xor(prod, 1);
      float ev = __expf(prod * psc);
      den += ev;
      a[0] += ev * blo(u0.y); a[1] += ev * bhi(u0.y);
      a[2] += ev * blo(u0.w); a[3] += ev * bhi(u0.w);
      a[4] += ev * blo(u1.y); a[5] += ev * bhi(u1.y);
      a[6] += ev * blo(u1.w); a[7] += ev * bhi(u1.w);
    }
  }
  float inv = 1.f / (den + 1e-16f);
#pragma unroll
  for (int i = 0; i < 8; i++) out[i] = a[i] * inv;
}

// -------- fused aggregation + GELU: 16 nodes per block (4 per wave) ---------
__global__ __launch_bounds__(256) void agg_all(
    const int* __restrict__ rs0, const int* __restrict__ dg0, const int* __restrict__ srcs0,
    const int* __restrict__ rs1, const int* __restrict__ dg1, const int* __restrict__ srcs1,
    const int* __restrict__ rs2, const int* __restrict__ dg2, const int* __restrict__ srcs2,
    const bf16* __restrict__ KV0, const bf16* __restrict__ KV1,
    const bf16* __restrict__ KV2, const float* __restrict__ pl,
    const bf16* __restrict__ Qb, bf16* __restrict__ AGGb)
{
  int n = blockIdx.x * 16 + (threadIdx.x >> 4);
  if (n >= N_TOT) return;
  int lane = threadIdx.x & 63;
  int p = lane & 15, h = p >> 1;
  uint4 qv = *(const uint4*)(Qb + (long)n * CCH + 8 * p);
  float q[8];
  q[0] = blo(qv.x); q[1] = bhi(qv.x); q[2] = blo(qv.y); q[3] = bhi(qv.y);
  q[4] = blo(qv.z); q[5] = bhi(qv.z); q[6] = blo(qv.w); q[7] = bhi(qv.w);
  float m[8];
  if (n < N_STMT) {
    float m0[8], m2[8];
    relmsg_grp(rs0[n], dg0[n], srcs0, KV0, pl[h] * 0.25f, q, lane, m0);
    relmsg_grp(rs2[n], dg2[n], srcs2, KV2, pl[16 + h] * 0.25f, q, lane, m2);
#pragma unroll
    for (int i = 0; i < 8; i++) m[i] = m0[i] + m2[i];
  } else {
    int nf = n - N_STMT;
    relmsg_grp(rs1[nf], dg1[nf], srcs1, KV1, pl[8 + h] * 0.25f, q, lane, m);
  }
  short8 o;
#pragma unroll
  for (int i = 0; i < 8; i++) o[i] = f2bs(gelu_f(m[i]));
  *(short8*)(AGGb + (long)n * CCH + 8 * p) = o;
}

__global__ __launch_bounds__(256) void zero_out_k(float* __restrict__ out)
{
  long i = ((long)blockIdx.x * 256 + threadIdx.x) * 4;
  *(float4*)(out + i) = make_float4(0.f, 0.f, 0.f, 0.f);
}

extern "C" void kernel_launch(void* const* d_in, const int* in_sizes, int n_in,
                              void* d_out, int out_size, void* d_ws, size_t ws_size,
                              hipStream_t stream)
{
  const int* tok_s = (const int*)d_in[0];
  const int* tok_f = (const int*)d_in[1];
  const int* esrc[3] = {(const int*)d_in[2], (const int*)d_in[4], (const int*)d_in[6]};
  const int* edst[3] = {(const int*)d_in[3], (const int*)d_in[5], (const int*)d_in[7]};
  const float* emb   = (const float*)d_in[8];
  const float* lin_w = (const float*)d_in[9];
  const float* lin_b = (const float*)d_in[10];
  const float* kw = (const float*)d_in[11];
  const float* kb = (const float*)d_in[12];
  const float* qw = (const float*)d_in[13];
  const float* qb = (const float*)d_in[14];
  const float* vw = (const float*)d_in[15];
  const float* vb = (const float*)d_in[16];
  const float* aw = (const float*)d_in[17];
  const float* ab = (const float*)d_in[18];
  const float* skip  = (const float*)d_in[19];
  const float* a_rel = (const float*)d_in[20];
  const float* m_rel = (const float*)d_in[21];
  const float* p_rel = (const float*)d_in[22];

  // ---- ws layout. Total 210,727,056 B. ----
  float* Bf   = (float*)d_ws;           // 12 x 128 fused biases
  bf16*  Xb   = (bf16*)(Bf + 1536);     // 19,200,000  residual stream
  bf16*  AGGb = Xb  + 19200000L;        // 19,200,000  (alias: pooled E)
  bf16*  KV0  = AGGb + 19200000L;       // 25,600,000  stmt r0 KV interleaved
  bf16*  KV1  = KV0 + 25600000L;        // 25,600,000  stmt r1 KV
  bf16*  KV2  = KV1 + 25600000L;        // 12,800,000  func r2 KV
  bf16*  WT   = KV2 + 12800000L;        //    163,840  10 transposed raw mats
  bf16*  WRT  = WT  + 163840L;          //    196,608  12 fused rel mats
  int*   ip   = (int*)(WRT + 196608L);
  int* deg[3]      = {ip, ip + 100000, ip + 150000};
  int* total       = ip + 250000;                      // 4 counters (3 used)
  int* rowstart[3] = {ip + 250004, ip + 350004, ip + 400004};
  int* srcs[3]     = {ip + 500004, ip + 700004, ip + 900004};
  int* pos         = ip + 1100004;                     // 200,000 (shared)
  bf16* EBF   = KV0;                    // 6,400,000 alias: bf16 emb table,
                                        // dead before KV0 is first written
  bf16*  Qb   = (bf16*)d_out;          // bf16 Q scratch in fp32 d_out,
  float* OUTF = (float*)d_out;         // consumed before epilogue overwrites

  const size_t NEED = (size_t)1536 * 4 + (size_t)102760448 * 2
                    + (size_t)1300004 * 4;
  if (ws_size < NEED) {            // soft-fail diagnostic: absmax == |ref|max
    zero_out_k<<<19200000 / 4 / 256, 256, 0, stream>>>(OUTF);
    return;
  }

  const int  Ntype[2] = {N_STMT, N_FUNC};
  const int  edt[3] = {0, 1, 0};
  const int  EB = (EDGES + 255) / 256;

  // ---- CSR build (per relation), reused by both layers ----
  hipMemsetAsync(ip, 0, (size_t)250004 * 4, stream);
  for (int r = 0; r < 3; r++) {
    int Nd = Ntype[edt[r]];
    csr_count<<<EB, 256, 0, stream>>>(edst[r], deg[r], pos);
    csr_alloc<<<(Nd + 255) / 256, 256, 0, stream>>>(deg[r], rowstart[r], total + r, Nd);
    csr_fill<<<EB, 256, 0, stream>>>(edst[r], esrc[r], rowstart[r], pos, srcs[r]);
  }

  // ---- one-time prep ----
  emb2bf<<<3125, 256, 0, stream>>>(emb, EBF);
  transp_w<<<dim3(64, 10), 256, 0, stream>>>(lin_w, qw, aw, WT);
  make_wr_all<<<dim3(64, 12), 256, 0, stream>>>(kw, kb, vw, vb, a_rel, m_rel, WRT, Bf);

  // ---- prologue: pooled embeddings -> fused per-type linear+relu -> Xb ----
  pool_embed<<<N_TOT / 4, 256, 0, stream>>>(tok_s, tok_f, EBF, AGGb);
  gemm_2t_reg<true, false, true><<<GS2 + GF2, 256, 0, stream>>>(
      AGGb, WT, WT + 16384, lin_b, lin_b + 128, nullptr, Xb, nullptr);

  const int GA = (N_STMT + 127) / 128;   // 782  (NM=3 stmt, rpb=128)
  const int GB = (N_STMT + 95) / 96;     // 1042 (NM=2 stmt, rpb=96)
  const int GF = (N_FUNC + 127) / 128;   // 391  (NM=3 func, rpb=128)

  for (int l = 0; l < 2; l++) {
    int z0 = l * 3 + 0, z1 = l * 3 + 1, z2 = l * 3 + 2;
    // stmt A: Q + KV(r0)
    gemm_qkv_reg<3, true><<<GA, 256, 0, stream>>>(
        Xb,
        WT + (2 + l * 2) * 16384, qb + (l * 2) * 128,
        WRT + z0 * 16384, Bf + z0 * 128,
        WRT + (6 + z0) * 16384, Bf + (6 + z0) * 128,
        Qb, KV0, N_STMT, 128);
    // stmt B: KV(r1) only (re-reads X; lower regs -> 4 waves/SIMD)
    gemm_qkv_reg<2, false><<<GB, 256, 0, stream>>>(
        Xb,
        WRT + z1 * 16384, Bf + z1 * 128,
        WRT + (6 + z1) * 16384, Bf + (6 + z1) * 128,
        nullptr, nullptr,
        nullptr, KV1, N_STMT, 96);
    // func: Q + KV(r2)
    gemm_qkv_reg<3, true><<<GF, 256, 0, stream>>>(
        Xb + (long)N_STMT * CCH,
        WT + (2 + l * 2 + 1) * 16384, qb + (l * 2 + 1) * 128,
        WRT + z2 * 16384, Bf + z2 * 128,
        WRT + (6 + z2) * 16384, Bf + (6 + z2) * 128,
        Qb + (long)N_STMT * CCH, KV2, N_FUNC, 128);
    // fused aggregation (+GELU) over all nodes, 16 nodes/block
    agg_all<<<(N_TOT + 15) / 16, 256, 0, stream>>>(
        rowstart[0], deg[0], srcs[0], rowstart[1], deg[1], srcs[1],
        rowstart[2], deg[2], srcs[2], KV0, KV1, KV2,
        p_rel + l * 24, Qb, AGGb);
    // fused out-proj + gated skip blend. l=0 -> Xb; l=1 -> fp32 d_out.
    if (l == 0)
      gemm_2t_reg<false, true, true><<<GS2 + GF2, 256, 0, stream>>>(
          AGGb, WT + 6 * 16384, WT + 7 * 16384, ab, ab + 128,
          Xb, Xb, skip);
    else
      gemm_2t_reg<false, true, false><<<GS2 + GF2, 256, 0, stream>>>(
          AGGb, WT + 8 * 16384, WT + 9 * 16384, ab + 256, ab + 384,
          Xb, OUTF, skip + 2);
  }
}